// Round 2
// baseline (4411.832 us; speedup 1.0000x reference)
//
#include <hip/hip_runtime.h>
#include <cstdint>
#include <cmath>

#define T_STEPS 1460
#define N_GRID  2000
#define UH_LEN  15
#define NZ      1e-6f
#define NB      32                   // 64-cell blocks (covers 2048 cells)
#define NPLANE  24                   // 23 used + 1 pad (16B-aligned record)
#define SLOT_FLOATS (NPLANE * 64)    // 1536 floats = 6144 B per (block, t)
#define DEPTH   8                    // LDS ring slots

static const size_t TG = (size_t)T_STEPS * N_GRID;

// sigmoid-bounded parameter transform (matches ref: lo + sigmoid(x)*(hi-lo))
__device__ __forceinline__ float pb(float x, float lo, float hi) {
    float s = 1.0f / (1.0f + expf(-x));
    return lo + s * (hi - lo);
}

__device__ __forceinline__ float clip01(float x) {
    return fminf(fmaxf(x, NZ), 1.0f);
}

// gate = round(sigmoid(x)) with round-half-to-even; (x>0) except near 0.
__device__ __forceinline__ float gatef(float x) {
    if (fabsf(x) < 1e-4f) {
        double s = 1.0 / (1.0 + exp(-(double)x));
        return (float)rint(s);
    }
    return (x > 0.0f) ? 1.0f : 0.0f;
}

// ---------------------------------------------------------------------------
// Kernel 1: per-cell unit hydrograph weights (softmax over 15 lags, 2 sets)
// ---------------------------------------------------------------------------
__global__ __launch_bounds__(256)
void uh_kernel(const float* __restrict__ hyb,
               float* __restrict__ uh1, float* __restrict__ uh2)
{
    const int g = blockIdx.x * 256 + threadIdx.x;
    if (g >= N_GRID) return;
    const float* h = hyb + (size_t)g * 32;
    const float a1 = pb(h[28], 0.3f, 20.0f);
    const float b1 = pb(h[29], 0.01f, 5.0f);
    const float a2 = pb(h[30], 0.5f, 13.0f);
    const float b2 = pb(h[31], 0.15f, 1.5f);

    float lw[UH_LEN];
    {
        float m = -1e30f;
        #pragma unroll
        for (int k = 0; k < UH_LEN; ++k) {
            const float kk = (float)(k + 1);
            lw[k] = (a1 - 1.0f) * logf(kk) - kk / b1;
            m = fmaxf(m, lw[k]);
        }
        float s = 0.0f;
        #pragma unroll
        for (int k = 0; k < UH_LEN; ++k) { lw[k] = expf(lw[k] - m); s += lw[k]; }
        const float inv = 1.0f / s;
        #pragma unroll
        for (int k = 0; k < UH_LEN; ++k) uh1[k * N_GRID + g] = lw[k] * inv;
    }
    {
        float m = -1e30f;
        #pragma unroll
        for (int k = 0; k < UH_LEN; ++k) {
            const float kk = (float)(k + 1);
            lw[k] = (a2 - 1.0f) * logf(kk) - kk / b2;
            m = fmaxf(m, lw[k]);
        }
        float s = 0.0f;
        #pragma unroll
        for (int k = 0; k < UH_LEN; ++k) { lw[k] = expf(lw[k] - m); s += lw[k]; }
        const float inv = 1.0f / s;
        #pragma unroll
        for (int k = 0; k < UH_LEN; ++k) uh2[k * N_GRID + g] = lw[k] * inv;
    }
}

// ---------------------------------------------------------------------------
// Kernel P: parallel pre-pass -> blocked stream, QUAD-INTERLEAVED layout.
// Slot for (b,t): 6 quads; quad q holds planes 4q..4q+3 as float4 per cell:
//   addr (floats): (q*64 + c)*4 + j   == one float4 per (q, cell).
//   q0 = {temp, pet, pshed, wi0}
//   q1 = {wi1, wi2, wi3, wi4}
//   q2 = {wi5, wb0, wb1, wb2}
//   q3 = {wb3, wb4, wb5, wc0}
//   q4 = {wc1, wc2, wc3, wc4}
//   q5 = {wc5, g0, g1, 0}
// This lets the scan read a whole slot with 6 ds_read_b128 per lane, and
// prep writes 6 coalesced float4 stores per cell.
// gate byte plane (t,g): bit0=g4 bit1=g5 (for routing).
// ---------------------------------------------------------------------------
__global__ __launch_bounds__(256)
void prep_kernel(const float* __restrict__ xphy,
                 const float* __restrict__ wts,
                 const float* __restrict__ hyb,
                 float* __restrict__ stream,
                 unsigned char* __restrict__ gate_o)
{
    const int gid = blockIdx.x * 256 + threadIdx.x;  // 0..2047
    if (gid >= NB * 64) return;
    const int t = blockIdx.y;
    const int b = gid >> 6, c = gid & 63;
    float4* sp4 = (float4*)(stream + ((size_t)b * T_STEPS + t) * SLOT_FLOATS);

    if (gid >= N_GRID) {    // pad cells: write zeros (defined, harmless)
        const float4 z = make_float4(0.f, 0.f, 0.f, 0.f);
        #pragma unroll
        for (int q = 0; q < 6; ++q) sp4[q * 64 + c] = z;
        return;
    }

    const size_t idx = (size_t)t * N_GRID + gid;
    const float* xp = xphy + idx * 3;
    const float prcp = xp[0], temp = xp[1], pet = xp[2];

    float w[24];
    const float4* wp = (const float4*)(wts + idx * 24);
    #pragma unroll
    for (int k = 0; k < 6; ++k) {
        float4 v = wp[k];
        w[4*k] = v.x; w[4*k+1] = v.y; w[4*k+2] = v.z; w[4*k+3] = v.w;
    }

    float e[18];
    #pragma unroll
    for (int k = 0; k < 18; ++k) e[k] = __expf(w[k]);
    float s0 = 0.f, s1 = 0.f, s2 = 0.f;
    #pragma unroll
    for (int k = 0; k < 6; ++k) { s0 += e[k]; s1 += e[6+k]; s2 += e[12+k]; }
    const float r0 = 1.0f / s0, r1 = 1.0f / s1, r2 = 1.0f / s2;

    const float g0 = gatef(w[18]);
    const float g1 = gatef(w[19]);
    const float g2 = gatef(w[20]);
    const float g3 = gatef(w[21]);
    const float g4 = gatef(w[22]);
    const float g5 = gatef(w[23]);

    const float* h = hyb + (size_t)gid * 32;
    const float fc = pb(h[24], 0.0f, 1.0f);
    const float fs = pb(h[25], 0.0f, 1.0f);
    const float canopy = pet * (fc * (1.0f - fs));
    const float pshed = (temp >= 0.0f) ? fmaxf(prcp - canopy * g2, 0.0f)
                                       : fmaxf(prcp - canopy * g3, 0.0f);

    sp4[0 * 64 + c] = make_float4(temp, pet, pshed, e[0] * r0);
    sp4[1 * 64 + c] = make_float4(e[1] * r0, e[2] * r0, e[3] * r0, e[4] * r0);
    sp4[2 * 64 + c] = make_float4(e[5] * r0, e[6] * r1, e[7] * r1, e[8] * r1);
    sp4[3 * 64 + c] = make_float4(e[9] * r1, e[10] * r1, e[11] * r1, e[12] * r2);
    sp4[4 * 64 + c] = make_float4(e[13] * r2, e[14] * r2, e[15] * r2, e[16] * r2);
    sp4[5 * 64 + c] = make_float4(e[17] * r2, g0, g1, 0.0f);
    gate_o[idx] = (unsigned char)((g4 > 0.5f ? 1 : 0) | (g5 > 0.5f ? 2 : 0));
}

// ---------------------------------------------------------------------------
// Async global->LDS: one slot = 6 width-16 DMA loads (6144 B).
// LDS dest = wave-uniform base + lane*16 (lane0's pointer is the base).
// Each DMA instruction moves one full quad (1024 B), preserving layout.
// ---------------------------------------------------------------------------
__device__ __forceinline__ void load_slot(const float* sp, float* lp, int lane)
{
    #pragma unroll
    for (int i = 0; i < 6; ++i) {
        __builtin_amdgcn_global_load_lds(
            (const __attribute__((address_space(1))) void*)(sp + i * 256 + lane * 4),
            (__attribute__((address_space(3))) void*)(lp + i * 256 + lane * 4),
            16, 0, 0);
    }
}

// One slot's worth of per-cell values, held in registers (6 float4 = 24 VGPR).
struct Slot {
    float4 q0, q1, q2, q3, q4, q5;
};

__device__ __forceinline__ void read_slot_regs(const float* L, int lane, Slot& s)
{
    const float4* v = (const float4*)L;
    s.q0 = v[0 * 64 + lane];
    s.q1 = v[1 * 64 + lane];
    s.q2 = v[2 * 64 + lane];
    s.q3 = v[3 * 64 + lane];
    s.q4 = v[4 * 64 + lane];
    s.q5 = v[5 * 64 + lane];
}

// ---------------------------------------------------------------------------
// Kernel S: sequential scan, LDS ring (DEPTH=8, 7-deep HBM cover) PLUS a
// register double-buffer stage: slot t+1 is ds_read into registers while
// step t's math runs, so LDS latency hides under ~500+ cycles of math.
//
// vmcnt accounting (gfx9: stores also increment vmcnt). Per-iteration issue
// order: [L(t+7) x6] [wait] [ds_read slot t+1] [math] [S(t) x2].
// At iter t's wait we need slot t+1's loads (issued at iter t-6) complete.
// Younger ops: stores S(t-6..t-1) = 12, loads L(t+2..t+7) = 36  -> vmcnt(48).
// Warmup t<6: exact count is 36+2t; vmcnt(36) is exact at t=0 and safely
// stricter for 1<=t<=5. Tail (no more loads): vmcnt(0), ~7 iters, negligible.
// ---------------------------------------------------------------------------
__global__ __launch_bounds__(64, 1)
void scan_stream_kernel(const float* __restrict__ stream,
                        const float* __restrict__ hyb,
                        float* __restrict__ surf_o,
                        float* __restrict__ base_o)
{
    __shared__ float lds[DEPTH * SLOT_FLOATS];   // 48 KB
    const int lane = threadIdx.x;
    const int b = blockIdx.x;
    const int g = b * 64 + lane;
    const int gc = (g < N_GRID) ? g : (N_GRID - 1);   // clamp params for pad lanes

    const float* h = hyb + (size_t)gc * 32;
    const float inf_pc   = pb(h[0],  0.0f,   1.0f);
    const float hbv_beta = pb(h[1],  0.5f,   3.0f);
    const float vic_bexp = pb(h[2],  0.001f, 3.0f);
    const float hmets_al = pb(h[3],  0.3f,   1.0f);
    const float x3_1     = pb(h[4],  20.0f,  300.0f);
    const float bfc1     = pb(h[5],  -8.0f,  -2.0f);
    const float bfn1     = pb(h[6],  1.0f,   5.0f);
    const float bfmax1   = pb(h[7],  0.1f,   200.0f);
    const float lam      = pb(h[8],  0.1f,   0.5f);
    const float th1      = pb(h[9],  0.0001f,0.9999f);
    const float max_perc = pb(h[10], 1.0f,   50.0f);
    const float sfc      = pb(h[11], 0.0001f,0.9999f);
    const float crise    = pb(h[12], 0.1f,   50.0f);
    const float bfmax2   = pb(h[13], 0.1f,   100.0f);
    const float x3_2     = pb(h[14], 50.0f,  500.0f);
    const float bfc2     = pb(h[15], -8.0f,  -2.0f);
    const float bfn2     = pb(h[16], 1.0f,   5.0f);
    const float Tbf      = pb(h[17], -5.0f,  2.0f);
    const float Kf       = pb(h[18], 0.0f,   5.0f);
    const float ddf_min  = pb(h[19], 1.5f,   3.0f);
    const float ddf_plus = pb(h[20], 0.0f,   5.0f);
    const float Kcum     = pb(h[21], 0.01f,  0.2f);
    const float Tbm      = pb(h[22], -1.0f,  1.0f);
    const float swi      = pb(h[23], 0.0f,   0.4f);
    const float msw1     = pb(h[26], 50.0f,  500.0f);
    const float msw2     = pb(h[27], 50.0f,  500.0f);

    const float inv_msw1 = 1.0f / msw1;
    const float inv_msw2 = 1.0f / msw2;
    const float pow10_1  = powf(10.0f, bfc1);
    const float pow10_2  = powf(10.0f, bfc2);
    const float inv_x3_1 = 1.0f / x3_1;
    const float inv_x3_2 = 1.0f / x3_2;
    const float b1o4     = bfmax1 / expm1f(lam);
    const float b1o5     = bfmax1 / (1.0f - th1);
    const float perc_fac = max_perc / (1.0f - sfc);

    const float* src = stream + (size_t)b * T_STEPS * SLOT_FLOATS;

    float snow = NZ, liq = NZ, cum = NZ, sw1 = NZ, sw2 = NZ;

    // step t's math on a register slot; writes surf/base for step t.
    auto emit = [&](int t, const Slot& S) {
        const float temp  = S.q0.x, pet = S.q0.y, pshed = S.q0.z;
        const float a0 = S.q0.w, a1 = S.q1.x, a2 = S.q1.y;
        const float a3 = S.q1.z, a4 = S.q1.w, a5 = S.q2.x;
        const float f0 = S.q2.y, f1 = S.q2.z, f2 = S.q2.w;
        const float f3 = S.q3.x, f4 = S.q3.y, f5 = S.q3.z;
        const float c0 = S.q3.w, c1 = S.q4.x, c2 = S.q4.y;
        const float c3 = S.q4.z, c4 = S.q4.w, c5 = S.q5.x;
        const float g0 = S.q5.y, g1 = S.q5.z;

        const float rain  = (temp >= 0.0f) ? pshed : 0.0f;
        const float snowf = (temp <  0.0f) ? pshed : 0.0f;

        const float refreeze = fminf(liq, Kf * fmaxf(Tbf - temp, 0.0f));
        snow = snow + snowf + refreeze;
        liq  = liq - refreeze;
        const float ddf = ddf_min + ddf_plus * (1.0f - __expf(-Kcum * cum));
        const float melt = fminf(snow, ddf * fmaxf(temp - Tbm, 0.0f));
        snow -= melt;
        cum = (snow < NZ) ? NZ : (cum + melt);
        liq += melt;
        const float overflow = fmaxf(liq - swi * snow, 0.0f);
        liq -= overflow;
        const float wavail = rain + overflow;

        float sat1 = clip01(sw1 * inv_msw1);
        const float dry1 = clip01(1.0f - sat1);
        const float p1 = __powf(sat1, hbv_beta);
        const float p2 = __powf(dry1, vic_bexp);
        const float infil = wavail *
            (a0 * inf_pc + a1 * (1.0f - p1) + a2 * p2 +
             a3 * (hmets_al * dry1) + a4 * (1.0f - sat1 * sat1) + a5);

        sw1 += infil;
        const float excess = fmaxf(sw1 - msw1, 0.0f);
        sw1 -= excess;
        const float surf = wavail - infil + excess;

        sat1 = clip01(sw1 * inv_msw1);
        const float perc = fminf(g0 * perc_fac * fmaxf(sat1 - sfc, 0.0f), sw1);
        sw1 -= perc; sw2 += perc;

        float sat2 = clip01(sw2 * inv_msw2);
        sat1 = clip01(sw1 * inv_msw1);
        const float capi = fminf(g1 * crise * (1.0f - sat1) * sat2, sw2);
        sw2 -= capi; sw1 += capi;

        sat1 = clip01(sw1 * inv_msw1);
        const float et = fminf(pet * sat1, sw1);
        sw1 -= et;

        sat1 = clip01(sw1 * inv_msw1);
        const float q = sw1 * inv_x3_1;
        const float q4v = (q * q) * (q * q);
        const float gr1 = sw1 * (1.0f - __powf(1.0f + q4v, -0.25f));
        const float pw1 = __powf(sat1, bfn1);
        const float ex1 = __expf(lam * sat1) - 1.0f;
        const float bsum1 = f0 * gr1 + f1 * (pow10_1 * sw1) + f2 * (bfmax1 * pw1) +
                            f3 * (bfmax1 * sat1) + f4 * (b1o4 * ex1) +
                            f5 * (b1o5 * fmaxf(sat1 - th1, 0.0f));
        const float bf1 = fminf(bsum1, sw1);
        sw1 -= bf1;

        sat2 = clip01(sw2 * inv_msw2);
        const float u = sw2 * inv_x3_2;
        const float u4 = (u * u) * (u * u);
        const float gr2 = sw2 * (1.0f - __powf(1.0f + u4, -0.25f));
        const float pw2 = __powf(sat2, bfn2);
        const float t10 = pow10_2 * sw2;
        const float bsum2 = c0 * gr2 + c1 * t10 + c2 * (bfmax2 * pw2) +
                            c3 * (bfmax2 * sat2) + c4 * (bfmax2 * sat2 * sat2) +
                            c5 * (t10 * sat2);
        const float bf2 = fminf(bsum2, sw2);
        sw2 -= bf2;

        if (g < N_GRID) {
            const size_t o = (size_t)t * N_GRID + g;
            surf_o[o] = surf;
            base_o[o] = bf1 + bf2;
        }
    };

    // issue next DMA, fence, and read slot u+1 into dst (register prefetch).
    auto prefetch = [&](int u, Slot& dst) {
        if (u + 1 < T_STEPS) {
            if (u + DEPTH - 1 < T_STEPS) {
                const int ts = u + DEPTH - 1;
                load_slot(src + (size_t)ts * SLOT_FLOATS,
                          lds + (ts & (DEPTH - 1)) * SLOT_FLOATS, lane);
                if (u >= 6) {
                    asm volatile("s_waitcnt vmcnt(48)" ::: "memory");
                } else {
                    asm volatile("s_waitcnt vmcnt(36)" ::: "memory");
                }
            } else {
                asm volatile("s_waitcnt vmcnt(0)" ::: "memory");
            }
            read_slot_regs(lds + ((u + 1) & (DEPTH - 1)) * SLOT_FLOATS, lane, dst);
        }
    };

    // prologue: issue slots 0..6 (42 loads), wait slot 0 (36 younger), read it.
    for (int s = 0; s < DEPTH - 1; ++s)
        load_slot(src + (size_t)s * SLOT_FLOATS, lds + s * SLOT_FLOATS, lane);
    asm volatile("s_waitcnt vmcnt(36)" ::: "memory");

    Slot A, B;
    read_slot_regs(lds, lane, A);

    // T_STEPS is even; manual 2-stage pipeline with named register sets.
    for (int t = 0; t < T_STEPS; t += 2) {
        prefetch(t, B);       // DMA t+7, fence, ds_read slot t+1 -> B
        emit(t, A);           // math + stores for step t (hides B's ds_reads)
        prefetch(t + 1, A);   // DMA t+8, fence, ds_read slot t+2 -> A
        emit(t + 1, B);       // math + stores for step t+1 (hides A's ds_reads)
    }
}

// ---------------------------------------------------------------------------
// Kernel S-B (fallback for small ws): round-1 scan on raw inputs.
// ---------------------------------------------------------------------------
__global__ __launch_bounds__(64)
void scan_kernel(const float* __restrict__ xphy,
                 const float* __restrict__ wts,
                 const float* __restrict__ hyb,
                 float* __restrict__ surf_o,
                 float* __restrict__ base_o,
                 unsigned char* __restrict__ gate_o)
{
    const int g = blockIdx.x * 64 + threadIdx.x;
    if (g >= N_GRID) return;

    const float* h = hyb + (size_t)g * 32;
    const float inf_pc   = pb(h[0],  0.0f,   1.0f);
    const float hbv_beta = pb(h[1],  0.5f,   3.0f);
    const float vic_bexp = pb(h[2],  0.001f, 3.0f);
    const float hmets_al = pb(h[3],  0.3f,   1.0f);
    const float x3_1     = pb(h[4],  20.0f,  300.0f);
    const float bfc1     = pb(h[5],  -8.0f,  -2.0f);
    const float bfn1     = pb(h[6],  1.0f,   5.0f);
    const float bfmax1   = pb(h[7],  0.1f,   200.0f);
    const float lam      = pb(h[8],  0.1f,   0.5f);
    const float th1      = pb(h[9],  0.0001f,0.9999f);
    const float max_perc = pb(h[10], 1.0f,   50.0f);
    const float sfc      = pb(h[11], 0.0001f,0.9999f);
    const float crise    = pb(h[12], 0.1f,   50.0f);
    const float bfmax2   = pb(h[13], 0.1f,   100.0f);
    const float x3_2     = pb(h[14], 50.0f,  500.0f);
    const float bfc2     = pb(h[15], -8.0f,  -2.0f);
    const float bfn2     = pb(h[16], 1.0f,   5.0f);
    const float Tbf      = pb(h[17], -5.0f,  2.0f);
    const float Kf       = pb(h[18], 0.0f,   5.0f);
    const float ddf_min  = pb(h[19], 1.5f,   3.0f);
    const float ddf_plus = pb(h[20], 0.0f,   5.0f);
    const float Kcum     = pb(h[21], 0.01f,  0.2f);
    const float Tbm      = pb(h[22], -1.0f,  1.0f);
    const float swi      = pb(h[23], 0.0f,   0.4f);
    const float fc       = pb(h[24], 0.0f,   1.0f);
    const float fs       = pb(h[25], 0.0f,   1.0f);
    const float msw1     = pb(h[26], 50.0f,  500.0f);
    const float msw2     = pb(h[27], 50.0f,  500.0f);

    const float inv_msw1  = 1.0f / msw1;
    const float inv_msw2  = 1.0f / msw2;
    const float canopy_fac = fc * (1.0f - fs);
    const float pow10_1   = powf(10.0f, bfc1);
    const float pow10_2   = powf(10.0f, bfc2);
    const float inv_x3_1  = 1.0f / x3_1;
    const float inv_x3_2  = 1.0f / x3_2;
    const float b1o4      = bfmax1 / expm1f(lam);
    const float b1o5      = bfmax1 / (1.0f - th1);
    const float perc_fac  = max_perc / (1.0f - sfc);

    float snow = NZ, liq = NZ, cum = NZ, sw1 = NZ, sw2 = NZ;

    for (int t = 0; t < T_STEPS; ++t) {
        const size_t idx = (size_t)t * N_GRID + g;
        const float* xp = xphy + idx * 3;
        const float prcp = xp[0], temp = xp[1], pet = xp[2];
        float4 wc0, wc1, wc2, wc3, wc4, wc5;
        const float4* wp = (const float4*)(wts + idx * 24);
        wc0 = wp[0]; wc1 = wp[1]; wc2 = wp[2]; wc3 = wp[3]; wc4 = wp[4]; wc5 = wp[5];

        const float g0 = gatef(wc4.z);
        const float g1 = gatef(wc4.w);
        const float g2 = gatef(wc5.x);
        const float g3 = gatef(wc5.y);
        const float g4 = gatef(wc5.z);
        const float g5 = gatef(wc5.w);

        float rain  = (temp >= 0.0f) ? prcp : 0.0f;
        float snowf = (temp <  0.0f) ? prcp : 0.0f;
        const float canopy = pet * canopy_fac;
        rain  = fmaxf(rain  - canopy * g2, 0.0f);
        snowf = fmaxf(snowf - canopy * g3, 0.0f);

        const float refreeze = fminf(liq, Kf * fmaxf(Tbf - temp, 0.0f));
        snow = snow + snowf + refreeze;
        liq  = liq - refreeze;
        const float ddf = ddf_min + ddf_plus * (1.0f - __expf(-Kcum * cum));
        const float melt = fminf(snow, ddf * fmaxf(temp - Tbm, 0.0f));
        snow -= melt;
        cum = (snow < NZ) ? NZ : (cum + melt);
        liq += melt;
        const float overflow = fmaxf(liq - swi * snow, 0.0f);
        liq -= overflow;
        const float wavail = rain + overflow;

        float sat1 = clip01(sw1 * inv_msw1);
        const float dry1 = clip01(1.0f - sat1);
        const float e0 = __expf(wc0.x), e1 = __expf(wc0.y), e2 = __expf(wc0.z),
                    e3 = __expf(wc0.w), e4 = __expf(wc1.x), e5 = __expf(wc1.y);
        const float rsi = 1.0f / (e0 + e1 + e2 + e3 + e4 + e5);
        const float p1 = __powf(sat1, hbv_beta);
        const float p2 = __powf(dry1, vic_bexp);
        const float infil = wavail * rsi *
            (e0 * inf_pc + e1 * (1.0f - p1) + e2 * p2 +
             e3 * (hmets_al * dry1) + e4 * (1.0f - sat1 * sat1) + e5);

        sw1 += infil;
        const float excess = fmaxf(sw1 - msw1, 0.0f);
        sw1 -= excess;
        const float surf = wavail - infil + excess;

        sat1 = clip01(sw1 * inv_msw1);
        const float perc = fminf(g0 * perc_fac * fmaxf(sat1 - sfc, 0.0f), sw1);
        sw1 -= perc; sw2 += perc;

        float sat2 = clip01(sw2 * inv_msw2);
        sat1 = clip01(sw1 * inv_msw1);
        const float capi = fminf(g1 * crise * (1.0f - sat1) * sat2, sw2);
        sw2 -= capi; sw1 += capi;

        sat1 = clip01(sw1 * inv_msw1);
        const float et = fminf(pet * sat1, sw1);
        sw1 -= et;

        sat1 = clip01(sw1 * inv_msw1);
        const float f0 = __expf(wc1.z), f1 = __expf(wc1.w), f2 = __expf(wc2.x),
                    f3 = __expf(wc2.y), f4 = __expf(wc2.z), f5 = __expf(wc2.w);
        const float rb1 = 1.0f / (f0 + f1 + f2 + f3 + f4 + f5);
        const float q = sw1 * inv_x3_1;
        const float q4 = (q * q) * (q * q);
        const float gr1 = sw1 * (1.0f - __powf(1.0f + q4, -0.25f));
        const float pw1 = __powf(sat1, bfn1);
        const float ex1 = __expf(lam * sat1) - 1.0f;
        const float bsum1 = f0 * gr1 + f1 * (pow10_1 * sw1) + f2 * (bfmax1 * pw1) +
                            f3 * (bfmax1 * sat1) + f4 * (b1o4 * ex1) +
                            f5 * (b1o5 * fmaxf(sat1 - th1, 0.0f));
        const float bf1 = fminf(bsum1 * rb1, sw1);
        sw1 -= bf1;

        sat2 = clip01(sw2 * inv_msw2);
        const float c0 = __expf(wc3.x), c1 = __expf(wc3.y), c2 = __expf(wc3.z),
                    c3 = __expf(wc3.w), c4 = __expf(wc4.x), c5 = __expf(wc4.y);
        const float rb2 = 1.0f / (c0 + c1 + c2 + c3 + c4 + c5);
        const float u = sw2 * inv_x3_2;
        const float u4 = (u * u) * (u * u);
        const float gr2 = sw2 * (1.0f - __powf(1.0f + u4, -0.25f));
        const float pw2 = __powf(sat2, bfn2);
        const float t10 = pow10_2 * sw2;
        const float bsum2 = c0 * gr2 + c1 * t10 + c2 * (bfmax2 * pw2) +
                            c3 * (bfmax2 * sat2) + c4 * (bfmax2 * sat2 * sat2) +
                            c5 * (t10 * sat2);
        const float bf2 = fminf(bsum2 * rb2, sw2);
        sw2 -= bf2;

        surf_o[idx] = surf;
        base_o[idx] = bf1 + bf2;
        gate_o[idx] = (unsigned char)((g4 > 0.5f ? 1 : 0) | (g5 > 0.5f ? 2 : 0));
    }
}

// ---------------------------------------------------------------------------
// Kernel 3: unit-hydrograph routing + gate blend.
// ---------------------------------------------------------------------------
__global__ __launch_bounds__(256)
void route_kernel(const float* __restrict__ surf,
                  const float* __restrict__ base,
                  const float* __restrict__ uh1,
                  const float* __restrict__ uh2,
                  const unsigned char* __restrict__ gates,
                  float* __restrict__ out)
{
    const int g = blockIdx.x * 256 + threadIdx.x;
    if (g >= N_GRID) return;
    const int t = blockIdx.y;
    const size_t o = (size_t)t * N_GRID + g;

    const unsigned char gb = gates[o];
    const float s0 = surf[o];
    const float b0 = base[o];

    float accs = 0.0f, accb = 0.0f;
    #pragma unroll
    for (int lag = 0; lag < UH_LEN; ++lag) {
        const int tt = t - lag;
        const float sv = (tt >= 0) ? surf[(size_t)tt * N_GRID + g] : 0.0f;
        const float bv = (tt >= 0) ? base[(size_t)tt * N_GRID + g] : 0.0f;
        accs += uh1[lag * N_GRID + g] * sv;
        accb += uh2[lag * N_GRID + g] * bv;
    }
    const float qs = (gb & 1) ? accs : s0;
    const float qb = (gb & 2) ? accb : b0;
    out[o] = qs + qb;
}

// ---------------------------------------------------------------------------
extern "C" void kernel_launch(void* const* d_in, const int* in_sizes, int n_in,
                              void* d_out, int out_size, void* d_ws, size_t ws_size,
                              hipStream_t stream)
{
    const float* x_phy = (const float*)d_in[0];   // (T, G, 3)
    const float* wts   = (const float*)d_in[1];   // (T, G, 24)
    const float* hyb   = (const float*)d_in[2];   // (G, 32)
    float* out = (float*)d_out;                   // (T, G)

    const size_t stream_f = (size_t)NB * T_STEPS * SLOT_FLOATS;   // 71,761,920
    const size_t uh_f     = (size_t)UH_LEN * N_GRID;
    const size_t big_need = stream_f * 4 + TG * (2 * 4 + 1) + 2 * uh_f * 4; // ~313.6 MB

    if (ws_size >= big_need) {
        float* strm = (float*)d_ws;
        float* surf = strm + stream_f;
        float* base = surf + TG;
        float* uh1  = base + TG;
        float* uh2  = uh1 + uh_f;
        unsigned char* gbits = (unsigned char*)(uh2 + uh_f);

        prep_kernel<<<dim3((NB * 64) / 256, T_STEPS), dim3(256), 0, stream>>>(
            x_phy, wts, hyb, strm, gbits);
        uh_kernel<<<dim3((N_GRID + 255) / 256), dim3(256), 0, stream>>>(hyb, uh1, uh2);
        scan_stream_kernel<<<dim3(NB), dim3(64), 0, stream>>>(strm, hyb, surf, base);
        route_kernel<<<dim3((N_GRID + 255) / 256, T_STEPS), dim3(256), 0, stream>>>(
            surf, base, uh1, uh2, gbits, out);
    } else {
        float* surf = (float*)d_ws;
        float* base = surf + TG;
        float* uh1  = base + TG;
        float* uh2  = uh1 + uh_f;
        unsigned char* gbits = (unsigned char*)(uh2 + uh_f);

        uh_kernel<<<dim3((N_GRID + 255) / 256), dim3(256), 0, stream>>>(hyb, uh1, uh2);
        scan_kernel<<<dim3((N_GRID + 63) / 64), dim3(64), 0, stream>>>(
            x_phy, wts, hyb, surf, base, gbits);
        route_kernel<<<dim3((N_GRID + 255) / 256, T_STEPS), dim3(256), 0, stream>>>(
            surf, base, uh1, uh2, gbits, out);
    }
}

// Round 3
// 3810.336 us; speedup vs baseline: 1.1579x; 1.1579x over previous
//
#include <hip/hip_runtime.h>
#include <cstdint>
#include <cmath>

#define T_STEPS 1460
#define N_GRID  2000
#define UH_LEN  15
#define NZ      1e-6f
#define CPB     8                    // cells per block (8 x 250 = 2000, exact)
#define NBLK    250                  // scan blocks = active CUs
#define NPLANE  24                   // 23 used + 1 pad (16B-aligned record)
#define SLOT_FLOATS (NPLANE * CPB)   // 192 floats = 768 B per (block, t)
#define DEPTH   8                    // LDS ring slots (6 KB LDS)

static const size_t TG = (size_t)T_STEPS * N_GRID;

// sigmoid-bounded parameter transform (matches ref: lo + sigmoid(x)*(hi-lo))
__device__ __forceinline__ float pb(float x, float lo, float hi) {
    float s = 1.0f / (1.0f + expf(-x));
    return lo + s * (hi - lo);
}

__device__ __forceinline__ float clip01(float x) {
    return fminf(fmaxf(x, NZ), 1.0f);
}

// gate = round(sigmoid(x)) with round-half-to-even; (x>0) except near 0.
__device__ __forceinline__ float gatef(float x) {
    if (fabsf(x) < 1e-4f) {
        double s = 1.0 / (1.0 + exp(-(double)x));
        return (float)rint(s);
    }
    return (x > 0.0f) ? 1.0f : 0.0f;
}

// ---------------------------------------------------------------------------
// Kernel 1: per-cell unit hydrograph weights (softmax over 15 lags, 2 sets)
// ---------------------------------------------------------------------------
__global__ __launch_bounds__(256)
void uh_kernel(const float* __restrict__ hyb,
               float* __restrict__ uh1, float* __restrict__ uh2)
{
    const int g = blockIdx.x * 256 + threadIdx.x;
    if (g >= N_GRID) return;
    const float* h = hyb + (size_t)g * 32;
    const float a1 = pb(h[28], 0.3f, 20.0f);
    const float b1 = pb(h[29], 0.01f, 5.0f);
    const float a2 = pb(h[30], 0.5f, 13.0f);
    const float b2 = pb(h[31], 0.15f, 1.5f);

    float lw[UH_LEN];
    {
        float m = -1e30f;
        #pragma unroll
        for (int k = 0; k < UH_LEN; ++k) {
            const float kk = (float)(k + 1);
            lw[k] = (a1 - 1.0f) * logf(kk) - kk / b1;
            m = fmaxf(m, lw[k]);
        }
        float s = 0.0f;
        #pragma unroll
        for (int k = 0; k < UH_LEN; ++k) { lw[k] = expf(lw[k] - m); s += lw[k]; }
        const float inv = 1.0f / s;
        #pragma unroll
        for (int k = 0; k < UH_LEN; ++k) uh1[k * N_GRID + g] = lw[k] * inv;
    }
    {
        float m = -1e30f;
        #pragma unroll
        for (int k = 0; k < UH_LEN; ++k) {
            const float kk = (float)(k + 1);
            lw[k] = (a2 - 1.0f) * logf(kk) - kk / b2;
            m = fmaxf(m, lw[k]);
        }
        float s = 0.0f;
        #pragma unroll
        for (int k = 0; k < UH_LEN; ++k) { lw[k] = expf(lw[k] - m); s += lw[k]; }
        const float inv = 1.0f / s;
        #pragma unroll
        for (int k = 0; k < UH_LEN; ++k) uh2[k * N_GRID + g] = lw[k] * inv;
    }
}

// ---------------------------------------------------------------------------
// Kernel P: parallel pre-pass -> blocked stream, PER-CELL-contiguous layout.
// Slot for (b,t): CPB cells x 24 floats (6 float4 quads per cell):
//   q0 = {temp, pet, pshed, wi0}
//   q1 = {wi1, wi2, wi3, wi4}
//   q2 = {wi5, wb0, wb1, wb2}
//   q3 = {wb3, wb4, wb5, wc0}
//   q4 = {wc1, wc2, wc3, wc4}
//   q5 = {wc5, g0, g1, 0}
// Slot = 768 B -> one exec-masked global_load_lds (lanes 0..47 x 16 B).
// gate byte plane (t,g): bit0=g4 bit1=g5 (for routing).
// ---------------------------------------------------------------------------
__global__ __launch_bounds__(256)
void prep_kernel(const float* __restrict__ xphy,
                 const float* __restrict__ wts,
                 const float* __restrict__ hyb,
                 float* __restrict__ stream,
                 unsigned char* __restrict__ gate_o)
{
    const int gid = blockIdx.x * 256 + threadIdx.x;  // 0..2047
    if (gid >= N_GRID) return;
    const int t = blockIdx.y;
    const int b = gid >> 3, c = gid & 7;             // block, cell-in-block
    float4* sp4 = (float4*)(stream + ((size_t)b * T_STEPS + t) * SLOT_FLOATS
                            + (size_t)c * NPLANE);

    const size_t idx = (size_t)t * N_GRID + gid;
    const float* xp = xphy + idx * 3;
    const float prcp = xp[0], temp = xp[1], pet = xp[2];

    float w[24];
    const float4* wp = (const float4*)(wts + idx * 24);
    #pragma unroll
    for (int k = 0; k < 6; ++k) {
        float4 v = wp[k];
        w[4*k] = v.x; w[4*k+1] = v.y; w[4*k+2] = v.z; w[4*k+3] = v.w;
    }

    float e[18];
    #pragma unroll
    for (int k = 0; k < 18; ++k) e[k] = __expf(w[k]);
    float s0 = 0.f, s1 = 0.f, s2 = 0.f;
    #pragma unroll
    for (int k = 0; k < 6; ++k) { s0 += e[k]; s1 += e[6+k]; s2 += e[12+k]; }
    const float r0 = 1.0f / s0, r1 = 1.0f / s1, r2 = 1.0f / s2;

    const float g0 = gatef(w[18]);
    const float g1 = gatef(w[19]);
    const float g2 = gatef(w[20]);
    const float g3 = gatef(w[21]);
    const float g4 = gatef(w[22]);
    const float g5 = gatef(w[23]);

    const float* h = hyb + (size_t)gid * 32;
    const float fc = pb(h[24], 0.0f, 1.0f);
    const float fs = pb(h[25], 0.0f, 1.0f);
    const float canopy = pet * (fc * (1.0f - fs));
    const float pshed = (temp >= 0.0f) ? fmaxf(prcp - canopy * g2, 0.0f)
                                       : fmaxf(prcp - canopy * g3, 0.0f);

    sp4[0] = make_float4(temp, pet, pshed, e[0] * r0);
    sp4[1] = make_float4(e[1] * r0, e[2] * r0, e[3] * r0, e[4] * r0);
    sp4[2] = make_float4(e[5] * r0, e[6] * r1, e[7] * r1, e[8] * r1);
    sp4[3] = make_float4(e[9] * r1, e[10] * r1, e[11] * r1, e[12] * r2);
    sp4[4] = make_float4(e[13] * r2, e[14] * r2, e[15] * r2, e[16] * r2);
    sp4[5] = make_float4(e[17] * r2, g0, g1, 0.0f);
    gate_o[idx] = (unsigned char)((g4 > 0.5f ? 1 : 0) | (g5 > 0.5f ? 2 : 0));
}

// ---------------------------------------------------------------------------
// Async global->LDS: one slot = ONE width-16 DMA op, lanes 0..47 (768 B).
// LDS dest = wave-uniform base + lane*16; exec mask trims to 48 lanes.
// ---------------------------------------------------------------------------
__device__ __forceinline__ void load_slot(const float* sp, float* lp, int lane)
{
    if (lane < 48) {
        __builtin_amdgcn_global_load_lds(
            (const __attribute__((address_space(1))) void*)(sp + lane * 4),
            (__attribute__((address_space(3))) void*)(lp + lane * 4),
            16, 0, 0);
    }
}

// ---------------------------------------------------------------------------
// Kernel S: sequential scan spread over 250 CUs (8 cells each).
// Round-1 consume structure (wait -> ds_read -> math); the round-2 register
// double-buffer regressed and is reverted.
//
// vmcnt accounting (gfx9: stores also count). Per-iter vmem ops:
//   1 global_load_lds (slot t+7) + 2 exec-masked stores = 3.
// At iter t's wait, ops younger than slot t's load:
//   steady (t>=7): 7 loads (t+1..t+7) + 14 stores (t-7..t-1) -> vmcnt(21)
//   warmup (t<7):  7 + 2t -> vmcnt(7) (exact at t=0, stricter after)
//   tail: vmcnt(0) (few iters, negligible)
// ---------------------------------------------------------------------------
__global__ __launch_bounds__(64, 1)
void scan_stream_kernel(const float* __restrict__ stream,
                        const float* __restrict__ hyb,
                        float* __restrict__ surf_o,
                        float* __restrict__ base_o)
{
    __shared__ float lds[DEPTH * SLOT_FLOATS];   // 6 KB
    const int lane = threadIdx.x;
    const int b = blockIdx.x;
    const int cell = lane & (CPB - 1);           // lanes 8..63 mirror cell lane&7
    const int g = b * CPB + cell;                // always < N_GRID (250*8=2000)
    const bool live = (lane < CPB);

    const float* h = hyb + (size_t)g * 32;
    const float inf_pc   = pb(h[0],  0.0f,   1.0f);
    const float hbv_beta = pb(h[1],  0.5f,   3.0f);
    const float vic_bexp = pb(h[2],  0.001f, 3.0f);
    const float hmets_al = pb(h[3],  0.3f,   1.0f);
    const float x3_1     = pb(h[4],  20.0f,  300.0f);
    const float bfc1     = pb(h[5],  -8.0f,  -2.0f);
    const float bfn1     = pb(h[6],  1.0f,   5.0f);
    const float bfmax1   = pb(h[7],  0.1f,   200.0f);
    const float lam      = pb(h[8],  0.1f,   0.5f);
    const float th1      = pb(h[9],  0.0001f,0.9999f);
    const float max_perc = pb(h[10], 1.0f,   50.0f);
    const float sfc      = pb(h[11], 0.0001f,0.9999f);
    const float crise    = pb(h[12], 0.1f,   50.0f);
    const float bfmax2   = pb(h[13], 0.1f,   100.0f);
    const float x3_2     = pb(h[14], 50.0f,  500.0f);
    const float bfc2     = pb(h[15], -8.0f,  -2.0f);
    const float bfn2     = pb(h[16], 1.0f,   5.0f);
    const float Tbf      = pb(h[17], -5.0f,  2.0f);
    const float Kf       = pb(h[18], 0.0f,   5.0f);
    const float ddf_min  = pb(h[19], 1.5f,   3.0f);
    const float ddf_plus = pb(h[20], 0.0f,   5.0f);
    const float Kcum     = pb(h[21], 0.01f,  0.2f);
    const float Tbm      = pb(h[22], -1.0f,  1.0f);
    const float swi      = pb(h[23], 0.0f,   0.4f);
    const float msw1     = pb(h[26], 50.0f,  500.0f);
    const float msw2     = pb(h[27], 50.0f,  500.0f);

    const float inv_msw1 = 1.0f / msw1;
    const float inv_msw2 = 1.0f / msw2;
    const float pow10_1  = powf(10.0f, bfc1);
    const float pow10_2  = powf(10.0f, bfc2);
    const float inv_x3_1 = 1.0f / x3_1;
    const float inv_x3_2 = 1.0f / x3_2;
    const float b1o4     = bfmax1 / expm1f(lam);
    const float b1o5     = bfmax1 / (1.0f - th1);
    const float perc_fac = max_perc / (1.0f - sfc);

    const float* src = stream + (size_t)b * T_STEPS * SLOT_FLOATS;

    // prologue: issue slots 0..DEPTH-2 (7 DMA ops outstanding)
    for (int s = 0; s < DEPTH - 1; ++s)
        load_slot(src + (size_t)s * SLOT_FLOATS, lds + s * SLOT_FLOATS, lane);

    float snow = NZ, liq = NZ, cum = NZ, sw1 = NZ, sw2 = NZ;

    for (int t = 0; t < T_STEPS; ++t) {
        if (t + DEPTH - 1 < T_STEPS) {
            const int ts = t + DEPTH - 1;
            load_slot(src + (size_t)ts * SLOT_FLOATS,
                      lds + (ts & (DEPTH - 1)) * SLOT_FLOATS, lane);
            if (t >= DEPTH - 1) {
                asm volatile("s_waitcnt vmcnt(21)" ::: "memory");
            } else {
                asm volatile("s_waitcnt vmcnt(7)" ::: "memory");
            }
        } else {
            asm volatile("s_waitcnt vmcnt(0)" ::: "memory");
        }

        const float4* v = (const float4*)(lds + (t & (DEPTH - 1)) * SLOT_FLOATS
                                          + (size_t)cell * NPLANE);
        const float4 q0 = v[0], q1 = v[1], q2 = v[2];
        const float4 q3 = v[3], q4r = v[4], q5 = v[5];

        const float temp  = q0.x, pet = q0.y, pshed = q0.z;
        const float a0 = q0.w, a1 = q1.x, a2 = q1.y;
        const float a3 = q1.z, a4 = q1.w, a5 = q2.x;
        const float f0 = q2.y, f1 = q2.z, f2 = q2.w;
        const float f3 = q3.x, f4 = q3.y, f5 = q3.z;
        const float c0 = q3.w, c1 = q4r.x, c2 = q4r.y;
        const float c3 = q4r.z, c4 = q4r.w, c5 = q5.x;
        const float g0 = q5.y, g1 = q5.z;

        // === step math (identical to verified round-1) ===
        const float rain  = (temp >= 0.0f) ? pshed : 0.0f;
        const float snowf = (temp <  0.0f) ? pshed : 0.0f;

        const float refreeze = fminf(liq, Kf * fmaxf(Tbf - temp, 0.0f));
        snow = snow + snowf + refreeze;
        liq  = liq - refreeze;
        const float ddf = ddf_min + ddf_plus * (1.0f - __expf(-Kcum * cum));
        const float melt = fminf(snow, ddf * fmaxf(temp - Tbm, 0.0f));
        snow -= melt;
        cum = (snow < NZ) ? NZ : (cum + melt);
        liq += melt;
        const float overflow = fmaxf(liq - swi * snow, 0.0f);
        liq -= overflow;
        const float wavail = rain + overflow;

        float sat1 = clip01(sw1 * inv_msw1);
        const float dry1 = clip01(1.0f - sat1);
        const float p1 = __powf(sat1, hbv_beta);
        const float p2 = __powf(dry1, vic_bexp);
        const float infil = wavail *
            (a0 * inf_pc + a1 * (1.0f - p1) + a2 * p2 +
             a3 * (hmets_al * dry1) + a4 * (1.0f - sat1 * sat1) + a5);

        sw1 += infil;
        const float excess = fmaxf(sw1 - msw1, 0.0f);
        sw1 -= excess;
        const float surf = wavail - infil + excess;

        sat1 = clip01(sw1 * inv_msw1);
        const float perc = fminf(g0 * perc_fac * fmaxf(sat1 - sfc, 0.0f), sw1);
        sw1 -= perc; sw2 += perc;

        float sat2 = clip01(sw2 * inv_msw2);
        sat1 = clip01(sw1 * inv_msw1);
        const float capi = fminf(g1 * crise * (1.0f - sat1) * sat2, sw2);
        sw2 -= capi; sw1 += capi;

        sat1 = clip01(sw1 * inv_msw1);
        const float et = fminf(pet * sat1, sw1);
        sw1 -= et;

        sat1 = clip01(sw1 * inv_msw1);
        const float q = sw1 * inv_x3_1;
        const float q4 = (q * q) * (q * q);
        const float gr1 = sw1 * (1.0f - __powf(1.0f + q4, -0.25f));
        const float pw1 = __powf(sat1, bfn1);
        const float ex1 = __expf(lam * sat1) - 1.0f;
        const float bsum1 = f0 * gr1 + f1 * (pow10_1 * sw1) + f2 * (bfmax1 * pw1) +
                            f3 * (bfmax1 * sat1) + f4 * (b1o4 * ex1) +
                            f5 * (b1o5 * fmaxf(sat1 - th1, 0.0f));
        const float bf1 = fminf(bsum1, sw1);
        sw1 -= bf1;

        sat2 = clip01(sw2 * inv_msw2);
        const float u = sw2 * inv_x3_2;
        const float u4 = (u * u) * (u * u);
        const float gr2 = sw2 * (1.0f - __powf(1.0f + u4, -0.25f));
        const float pw2 = __powf(sat2, bfn2);
        const float t10 = pow10_2 * sw2;
        const float bsum2 = c0 * gr2 + c1 * t10 + c2 * (bfmax2 * pw2) +
                            c3 * (bfmax2 * sat2) + c4 * (bfmax2 * sat2 * sat2) +
                            c5 * (t10 * sat2);
        const float bf2 = fminf(bsum2, sw2);
        sw2 -= bf2;

        if (live) {
            const size_t o = (size_t)t * N_GRID + g;
            surf_o[o] = surf;
            base_o[o] = bf1 + bf2;
        }
    }
}

// ---------------------------------------------------------------------------
// Kernel S-B (fallback for small ws): round-1 scan on raw inputs.
// ---------------------------------------------------------------------------
__global__ __launch_bounds__(64)
void scan_kernel(const float* __restrict__ xphy,
                 const float* __restrict__ wts,
                 const float* __restrict__ hyb,
                 float* __restrict__ surf_o,
                 float* __restrict__ base_o,
                 unsigned char* __restrict__ gate_o)
{
    const int g = blockIdx.x * 64 + threadIdx.x;
    if (g >= N_GRID) return;

    const float* h = hyb + (size_t)g * 32;
    const float inf_pc   = pb(h[0],  0.0f,   1.0f);
    const float hbv_beta = pb(h[1],  0.5f,   3.0f);
    const float vic_bexp = pb(h[2],  0.001f, 3.0f);
    const float hmets_al = pb(h[3],  0.3f,   1.0f);
    const float x3_1     = pb(h[4],  20.0f,  300.0f);
    const float bfc1     = pb(h[5],  -8.0f,  -2.0f);
    const float bfn1     = pb(h[6],  1.0f,   5.0f);
    const float bfmax1   = pb(h[7],  0.1f,   200.0f);
    const float lam      = pb(h[8],  0.1f,   0.5f);
    const float th1      = pb(h[9],  0.0001f,0.9999f);
    const float max_perc = pb(h[10], 1.0f,   50.0f);
    const float sfc      = pb(h[11], 0.0001f,0.9999f);
    const float crise    = pb(h[12], 0.1f,   50.0f);
    const float bfmax2   = pb(h[13], 0.1f,   100.0f);
    const float x3_2     = pb(h[14], 50.0f,  500.0f);
    const float bfc2     = pb(h[15], -8.0f,  -2.0f);
    const float bfn2     = pb(h[16], 1.0f,   5.0f);
    const float Tbf      = pb(h[17], -5.0f,  2.0f);
    const float Kf       = pb(h[18], 0.0f,   5.0f);
    const float ddf_min  = pb(h[19], 1.5f,   3.0f);
    const float ddf_plus = pb(h[20], 0.0f,   5.0f);
    const float Kcum     = pb(h[21], 0.01f,  0.2f);
    const float Tbm      = pb(h[22], -1.0f,  1.0f);
    const float swi      = pb(h[23], 0.0f,   0.4f);
    const float fc       = pb(h[24], 0.0f,   1.0f);
    const float fs       = pb(h[25], 0.0f,   1.0f);
    const float msw1     = pb(h[26], 50.0f,  500.0f);
    const float msw2     = pb(h[27], 50.0f,  500.0f);

    const float inv_msw1  = 1.0f / msw1;
    const float inv_msw2  = 1.0f / msw2;
    const float canopy_fac = fc * (1.0f - fs);
    const float pow10_1   = powf(10.0f, bfc1);
    const float pow10_2   = powf(10.0f, bfc2);
    const float inv_x3_1  = 1.0f / x3_1;
    const float inv_x3_2  = 1.0f / x3_2;
    const float b1o4      = bfmax1 / expm1f(lam);
    const float b1o5      = bfmax1 / (1.0f - th1);
    const float perc_fac  = max_perc / (1.0f - sfc);

    float snow = NZ, liq = NZ, cum = NZ, sw1 = NZ, sw2 = NZ;

    for (int t = 0; t < T_STEPS; ++t) {
        const size_t idx = (size_t)t * N_GRID + g;
        const float* xp = xphy + idx * 3;
        const float prcp = xp[0], temp = xp[1], pet = xp[2];
        float4 wc0, wc1, wc2, wc3, wc4, wc5;
        const float4* wp = (const float4*)(wts + idx * 24);
        wc0 = wp[0]; wc1 = wp[1]; wc2 = wp[2]; wc3 = wp[3]; wc4 = wp[4]; wc5 = wp[5];

        const float g0 = gatef(wc4.z);
        const float g1 = gatef(wc4.w);
        const float g2 = gatef(wc5.x);
        const float g3 = gatef(wc5.y);
        const float g4 = gatef(wc5.z);
        const float g5 = gatef(wc5.w);

        float rain  = (temp >= 0.0f) ? prcp : 0.0f;
        float snowf = (temp <  0.0f) ? prcp : 0.0f;
        const float canopy = pet * canopy_fac;
        rain  = fmaxf(rain  - canopy * g2, 0.0f);
        snowf = fmaxf(snowf - canopy * g3, 0.0f);

        const float refreeze = fminf(liq, Kf * fmaxf(Tbf - temp, 0.0f));
        snow = snow + snowf + refreeze;
        liq  = liq - refreeze;
        const float ddf = ddf_min + ddf_plus * (1.0f - __expf(-Kcum * cum));
        const float melt = fminf(snow, ddf * fmaxf(temp - Tbm, 0.0f));
        snow -= melt;
        cum = (snow < NZ) ? NZ : (cum + melt);
        liq += melt;
        const float overflow = fmaxf(liq - swi * snow, 0.0f);
        liq -= overflow;
        const float wavail = rain + overflow;

        float sat1 = clip01(sw1 * inv_msw1);
        const float dry1 = clip01(1.0f - sat1);
        const float e0 = __expf(wc0.x), e1 = __expf(wc0.y), e2 = __expf(wc0.z),
                    e3 = __expf(wc0.w), e4 = __expf(wc1.x), e5 = __expf(wc1.y);
        const float rsi = 1.0f / (e0 + e1 + e2 + e3 + e4 + e5);
        const float p1 = __powf(sat1, hbv_beta);
        const float p2 = __powf(dry1, vic_bexp);
        const float infil = wavail * rsi *
            (e0 * inf_pc + e1 * (1.0f - p1) + e2 * p2 +
             e3 * (hmets_al * dry1) + e4 * (1.0f - sat1 * sat1) + e5);

        sw1 += infil;
        const float excess = fmaxf(sw1 - msw1, 0.0f);
        sw1 -= excess;
        const float surf = wavail - infil + excess;

        sat1 = clip01(sw1 * inv_msw1);
        const float perc = fminf(g0 * perc_fac * fmaxf(sat1 - sfc, 0.0f), sw1);
        sw1 -= perc; sw2 += perc;

        float sat2 = clip01(sw2 * inv_msw2);
        sat1 = clip01(sw1 * inv_msw1);
        const float capi = fminf(g1 * crise * (1.0f - sat1) * sat2, sw2);
        sw2 -= capi; sw1 += capi;

        sat1 = clip01(sw1 * inv_msw1);
        const float et = fminf(pet * sat1, sw1);
        sw1 -= et;

        sat1 = clip01(sw1 * inv_msw1);
        const float f0 = __expf(wc1.z), f1 = __expf(wc1.w), f2 = __expf(wc2.x),
                    f3 = __expf(wc2.y), f4 = __expf(wc2.z), f5 = __expf(wc2.w);
        const float rb1 = 1.0f / (f0 + f1 + f2 + f3 + f4 + f5);
        const float q = sw1 * inv_x3_1;
        const float q4 = (q * q) * (q * q);
        const float gr1 = sw1 * (1.0f - __powf(1.0f + q4, -0.25f));
        const float pw1 = __powf(sat1, bfn1);
        const float ex1 = __expf(lam * sat1) - 1.0f;
        const float bsum1 = f0 * gr1 + f1 * (pow10_1 * sw1) + f2 * (bfmax1 * pw1) +
                            f3 * (bfmax1 * sat1) + f4 * (b1o4 * ex1) +
                            f5 * (b1o5 * fmaxf(sat1 - th1, 0.0f));
        const float bf1 = fminf(bsum1 * rb1, sw1);
        sw1 -= bf1;

        sat2 = clip01(sw2 * inv_msw2);
        const float c0 = __expf(wc3.x), c1 = __expf(wc3.y), c2 = __expf(wc3.z),
                    c3 = __expf(wc3.w), c4 = __expf(wc4.x), c5 = __expf(wc4.y);
        const float rb2 = 1.0f / (c0 + c1 + c2 + c3 + c4 + c5);
        const float u = sw2 * inv_x3_2;
        const float u4 = (u * u) * (u * u);
        const float gr2 = sw2 * (1.0f - __powf(1.0f + u4, -0.25f));
        const float pw2 = __powf(sat2, bfn2);
        const float t10 = pow10_2 * sw2;
        const float bsum2 = c0 * gr2 + c1 * t10 + c2 * (bfmax2 * pw2) +
                            c3 * (bfmax2 * sat2) + c4 * (bfmax2 * sat2 * sat2) +
                            c5 * (t10 * sat2);
        const float bf2 = fminf(bsum2 * rb2, sw2);
        sw2 -= bf2;

        surf_o[idx] = surf;
        base_o[idx] = bf1 + bf2;
        gate_o[idx] = (unsigned char)((g4 > 0.5f ? 1 : 0) | (g5 > 0.5f ? 2 : 0));
    }
}

// ---------------------------------------------------------------------------
// Kernel 3: unit-hydrograph routing + gate blend.
// ---------------------------------------------------------------------------
__global__ __launch_bounds__(256)
void route_kernel(const float* __restrict__ surf,
                  const float* __restrict__ base,
                  const float* __restrict__ uh1,
                  const float* __restrict__ uh2,
                  const unsigned char* __restrict__ gates,
                  float* __restrict__ out)
{
    const int g = blockIdx.x * 256 + threadIdx.x;
    if (g >= N_GRID) return;
    const int t = blockIdx.y;
    const size_t o = (size_t)t * N_GRID + g;

    const unsigned char gb = gates[o];
    const float s0 = surf[o];
    const float b0 = base[o];

    float accs = 0.0f, accb = 0.0f;
    #pragma unroll
    for (int lag = 0; lag < UH_LEN; ++lag) {
        const int tt = t - lag;
        const float sv = (tt >= 0) ? surf[(size_t)tt * N_GRID + g] : 0.0f;
        const float bv = (tt >= 0) ? base[(size_t)tt * N_GRID + g] : 0.0f;
        accs += uh1[lag * N_GRID + g] * sv;
        accb += uh2[lag * N_GRID + g] * bv;
    }
    const float qs = (gb & 1) ? accs : s0;
    const float qb = (gb & 2) ? accb : b0;
    out[o] = qs + qb;
}

// ---------------------------------------------------------------------------
extern "C" void kernel_launch(void* const* d_in, const int* in_sizes, int n_in,
                              void* d_out, int out_size, void* d_ws, size_t ws_size,
                              hipStream_t stream)
{
    const float* x_phy = (const float*)d_in[0];   // (T, G, 3)
    const float* wts   = (const float*)d_in[1];   // (T, G, 24)
    const float* hyb   = (const float*)d_in[2];   // (G, 32)
    float* out = (float*)d_out;                   // (T, G)

    const size_t stream_f = (size_t)NBLK * T_STEPS * SLOT_FLOATS;   // 70,080,000
    const size_t uh_f     = (size_t)UH_LEN * N_GRID;
    const size_t big_need = stream_f * 4 + TG * (2 * 4 + 1) + 2 * uh_f * 4; // ~307 MB

    if (ws_size >= big_need) {
        float* strm = (float*)d_ws;
        float* surf = strm + stream_f;
        float* base = surf + TG;
        float* uh1  = base + TG;
        float* uh2  = uh1 + uh_f;
        unsigned char* gbits = (unsigned char*)(uh2 + uh_f);

        prep_kernel<<<dim3((N_GRID + 255) / 256, T_STEPS), dim3(256), 0, stream>>>(
            x_phy, wts, hyb, strm, gbits);
        uh_kernel<<<dim3((N_GRID + 255) / 256), dim3(256), 0, stream>>>(hyb, uh1, uh2);
        scan_stream_kernel<<<dim3(NBLK), dim3(64), 0, stream>>>(strm, hyb, surf, base);
        route_kernel<<<dim3((N_GRID + 255) / 256, T_STEPS), dim3(256), 0, stream>>>(
            surf, base, uh1, uh2, gbits, out);
    } else {
        float* surf = (float*)d_ws;
        float* base = surf + TG;
        float* uh1  = base + TG;
        float* uh2  = uh1 + uh_f;
        unsigned char* gbits = (unsigned char*)(uh2 + uh_f);

        uh_kernel<<<dim3((N_GRID + 255) / 256), dim3(256), 0, stream>>>(hyb, uh1, uh2);
        scan_kernel<<<dim3((N_GRID + 63) / 64), dim3(64), 0, stream>>>(
            x_phy, wts, hyb, surf, base, gbits);
        route_kernel<<<dim3((N_GRID + 255) / 256, T_STEPS), dim3(256), 0, stream>>>(
            surf, base, uh1, uh2, gbits, out);
    }
}

// Round 4
// 3499.338 us; speedup vs baseline: 1.2608x; 1.0889x over previous
//
#include <hip/hip_runtime.h>
#include <cstdint>
#include <cmath>

#define T_STEPS 1460
#define N_GRID  2000
#define GPAD    2048                 // padded cell count (32 blocks x 64)
#define UH_LEN  15
#define NZ      1e-6f
#define NB      32                   // 64-cell blocks
#define NPLANE  24                   // 6 float4 quads per cell
#define SLOT_FLOATS (NPLANE * 64)    // 1536 floats = 6144 B per (block, t)
#define DEPTH   8                    // LDS ring slots (48 KB)

static const size_t TG  = (size_t)T_STEPS * N_GRID;
static const size_t TGP = (size_t)T_STEPS * GPAD;

// sigmoid-bounded parameter transform (matches ref: lo + sigmoid(x)*(hi-lo))
__device__ __forceinline__ float pb(float x, float lo, float hi) {
    float s = 1.0f / (1.0f + expf(-x));
    return lo + s * (hi - lo);
}

__device__ __forceinline__ float clip01(float x) {
    return fminf(fmaxf(x, NZ), 1.0f);
}

// gate = round(sigmoid(x)) with round-half-to-even; (x>0) except near 0.
__device__ __forceinline__ float gatef(float x) {
    if (fabsf(x) < 1e-4f) {
        double s = 1.0 / (1.0 + exp(-(double)x));
        return (float)rint(s);
    }
    return (x > 0.0f) ? 1.0f : 0.0f;
}

// ---------------------------------------------------------------------------
// Kernel 1: per-cell unit hydrograph weights (softmax over 15 lags, 2 sets)
// ---------------------------------------------------------------------------
__global__ __launch_bounds__(256)
void uh_kernel(const float* __restrict__ hyb,
               float* __restrict__ uh1, float* __restrict__ uh2)
{
    const int g = blockIdx.x * 256 + threadIdx.x;
    if (g >= N_GRID) return;
    const float* h = hyb + (size_t)g * 32;
    const float a1 = pb(h[28], 0.3f, 20.0f);
    const float b1 = pb(h[29], 0.01f, 5.0f);
    const float a2 = pb(h[30], 0.5f, 13.0f);
    const float b2 = pb(h[31], 0.15f, 1.5f);

    float lw[UH_LEN];
    {
        float m = -1e30f;
        #pragma unroll
        for (int k = 0; k < UH_LEN; ++k) {
            const float kk = (float)(k + 1);
            lw[k] = (a1 - 1.0f) * logf(kk) - kk / b1;
            m = fmaxf(m, lw[k]);
        }
        float s = 0.0f;
        #pragma unroll
        for (int k = 0; k < UH_LEN; ++k) { lw[k] = expf(lw[k] - m); s += lw[k]; }
        const float inv = 1.0f / s;
        #pragma unroll
        for (int k = 0; k < UH_LEN; ++k) uh1[k * N_GRID + g] = lw[k] * inv;
    }
    {
        float m = -1e30f;
        #pragma unroll
        for (int k = 0; k < UH_LEN; ++k) {
            const float kk = (float)(k + 1);
            lw[k] = (a2 - 1.0f) * logf(kk) - kk / b2;
            m = fmaxf(m, lw[k]);
        }
        float s = 0.0f;
        #pragma unroll
        for (int k = 0; k < UH_LEN; ++k) { lw[k] = expf(lw[k] - m); s += lw[k]; }
        const float inv = 1.0f / s;
        #pragma unroll
        for (int k = 0; k < UH_LEN; ++k) uh2[k * N_GRID + g] = lw[k] * inv;
    }
}

// ---------------------------------------------------------------------------
// Kernel P: parallel pre-pass -> blocked stream, QUAD-MAJOR layout with all
// per-cell constant factors FOLDED IN (removes ~14 multiplies from the scan):
//   float4 index (q*64 + c), slot = (b*T + t):
//   q0 = {temp, pet, pshed, K}        K   = a0*inf_pc + a1 + a4 + a5
//   q1 = {a1, a2, a3s, a4}            a3s = a3*hmets_alpha
//   q2 = {f0, f1s, f2s, f3s}          f1s = f1*10^bfc1, f2s/f3s = f*bfmax1
//   q3 = {f4s, f5s, c0, c1s}          f4s = f4*bfmax1/expm1(lam),
//                                     f5s = f5*bfmax1/(1-th1), c1s = c1*10^bfc2
//   q4 = {c2s, c3s, c4s, c5s}         c2s/c3s/c4s = c*bfmax2, c5s = c5*10^bfc2
//   q5 = {g0p, g1c, 0, 0}             g0p = g0*max_perc/(1-sfc), g1c = g1*crise
// scan reads 6 conflict-free ds_read_b128 per lane.
// ---------------------------------------------------------------------------
__global__ __launch_bounds__(256)
void prep_kernel(const float* __restrict__ xphy,
                 const float* __restrict__ wts,
                 const float* __restrict__ hyb,
                 float* __restrict__ stream,
                 unsigned char* __restrict__ gate_o)
{
    const int gid = blockIdx.x * 256 + threadIdx.x;  // 0..2047
    if (gid >= NB * 64) return;
    const int t = blockIdx.y;
    const int b = gid >> 6, c = gid & 63;
    float4* sp4 = (float4*)(stream + ((size_t)b * T_STEPS + t) * SLOT_FLOATS);

    if (gid >= N_GRID) {    // pad cells: zeros (defined, harmless math)
        const float4 z = make_float4(0.f, 0.f, 0.f, 0.f);
        #pragma unroll
        for (int q = 0; q < 6; ++q) sp4[q * 64 + c] = z;
        return;
    }

    const size_t idx = (size_t)t * N_GRID + gid;
    const float* xp = xphy + idx * 3;
    const float prcp = xp[0], temp = xp[1], pet = xp[2];

    float w[24];
    const float4* wp = (const float4*)(wts + idx * 24);
    #pragma unroll
    for (int k = 0; k < 6; ++k) {
        float4 v = wp[k];
        w[4*k] = v.x; w[4*k+1] = v.y; w[4*k+2] = v.z; w[4*k+3] = v.w;
    }

    float e[18];
    #pragma unroll
    for (int k = 0; k < 18; ++k) e[k] = __expf(w[k]);
    float s0 = 0.f, s1 = 0.f, s2 = 0.f;
    #pragma unroll
    for (int k = 0; k < 6; ++k) { s0 += e[k]; s1 += e[6+k]; s2 += e[12+k]; }
    const float r0 = 1.0f / s0, r1 = 1.0f / s1, r2 = 1.0f / s2;

    const float g0 = gatef(w[18]);
    const float g1 = gatef(w[19]);
    const float g2 = gatef(w[20]);
    const float g3 = gatef(w[21]);
    const float g4 = gatef(w[22]);
    const float g5 = gatef(w[23]);

    const float* h = hyb + (size_t)gid * 32;
    const float inf_pc   = pb(h[0],  0.0f,   1.0f);
    const float hmets_al = pb(h[3],  0.3f,   1.0f);
    const float bfc1     = pb(h[5],  -8.0f,  -2.0f);
    const float bfmax1   = pb(h[7],  0.1f,   200.0f);
    const float lam      = pb(h[8],  0.1f,   0.5f);
    const float th1      = pb(h[9],  0.0001f,0.9999f);
    const float max_perc = pb(h[10], 1.0f,   50.0f);
    const float sfc      = pb(h[11], 0.0001f,0.9999f);
    const float crise    = pb(h[12], 0.1f,   50.0f);
    const float bfmax2   = pb(h[13], 0.1f,   100.0f);
    const float bfc2     = pb(h[15], -8.0f,  -2.0f);
    const float fc       = pb(h[24], 0.0f,   1.0f);
    const float fs       = pb(h[25], 0.0f,   1.0f);

    const float pow10_1 = powf(10.0f, bfc1);
    const float pow10_2 = powf(10.0f, bfc2);
    const float b1o4    = bfmax1 / expm1f(lam);
    const float b1o5    = bfmax1 / (1.0f - th1);
    const float perc_fac = max_perc / (1.0f - sfc);

    const float canopy = pet * (fc * (1.0f - fs));
    const float pshed = (temp >= 0.0f) ? fmaxf(prcp - canopy * g2, 0.0f)
                                       : fmaxf(prcp - canopy * g3, 0.0f);

    const float a0 = e[0]*r0, a1 = e[1]*r0, a2 = e[2]*r0;
    const float a3 = e[3]*r0, a4 = e[4]*r0, a5 = e[5]*r0;
    const float f0 = e[6]*r1, f1 = e[7]*r1, f2 = e[8]*r1;
    const float f3 = e[9]*r1, f4 = e[10]*r1, f5 = e[11]*r1;
    const float c0v = e[12]*r2, c1v = e[13]*r2, c2v = e[14]*r2;
    const float c3v = e[15]*r2, c4v = e[16]*r2, c5v = e[17]*r2;

    const float K = a0 * inf_pc + a1 + a4 + a5;

    sp4[0 * 64 + c] = make_float4(temp, pet, pshed, K);
    sp4[1 * 64 + c] = make_float4(a1, a2, a3 * hmets_al, a4);
    sp4[2 * 64 + c] = make_float4(f0, f1 * pow10_1, f2 * bfmax1, f3 * bfmax1);
    sp4[3 * 64 + c] = make_float4(f4 * b1o4, f5 * b1o5, c0v, c1v * pow10_2);
    sp4[4 * 64 + c] = make_float4(c2v * bfmax2, c3v * bfmax2, c4v * bfmax2,
                                  c5v * pow10_2);
    sp4[5 * 64 + c] = make_float4(g0 * perc_fac, g1 * crise, 0.0f, 0.0f);
    gate_o[idx] = (unsigned char)((g4 > 0.5f ? 1 : 0) | (g5 > 0.5f ? 2 : 0));
}

// ---------------------------------------------------------------------------
// Async global->LDS: one slot = 6 width-16 DMA loads (6144 B), full wave.
// ---------------------------------------------------------------------------
__device__ __forceinline__ void load_slot(const float* sp, float* lp, int lane)
{
    #pragma unroll
    for (int i = 0; i < 6; ++i) {
        __builtin_amdgcn_global_load_lds(
            (const __attribute__((address_space(1))) void*)(sp + i * 256 + lane * 4),
            (__attribute__((address_space(3))) void*)(lp + i * 256 + lane * 4),
            16, 0, 0);
    }
}

// ---------------------------------------------------------------------------
// Kernel S: sequential scan, 32 blocks x 64 cells, LDS ring DEPTH=8.
// Branch-free body (unconditional stores into GPAD-padded buffers), loop
// split into warmup/steady/tail so no per-iter conditionals remain.
//
// vmcnt (gfx9: stores count): 8 vmem ops/iter (6 loads + 2 stores).
//   steady: younger than slot t's loads = 42 loads + 14 stores -> vmcnt(56)
//   warmup: 42 (+2t stores, waiting those is harmless) -> vmcnt(42)
//   tail:   vmcnt(0)
// ---------------------------------------------------------------------------
__global__ __launch_bounds__(64, 1)
void scan_stream_kernel(const float* __restrict__ stream,
                        const float* __restrict__ hyb,
                        float* __restrict__ surf_o,
                        float* __restrict__ base_o)
{
    __shared__ float lds[DEPTH * SLOT_FLOATS];   // 48 KB
    const int lane = threadIdx.x;
    const int b = blockIdx.x;
    const int g = b * 64 + lane;                      // 0..2047
    const int gc = (g < N_GRID) ? g : (N_GRID - 1);   // clamp params for pads

    const float* h = hyb + (size_t)gc * 32;
    const float hbv_beta = pb(h[1],  0.5f,   3.0f);
    const float vic_bexp = pb(h[2],  0.001f, 3.0f);
    const float x3_1     = pb(h[4],  20.0f,  300.0f);
    const float bfn1     = pb(h[6],  1.0f,   5.0f);
    const float lam      = pb(h[8],  0.1f,   0.5f);
    const float th1      = pb(h[9],  0.0001f,0.9999f);
    const float sfc      = pb(h[11], 0.0001f,0.9999f);
    const float x3_2     = pb(h[14], 50.0f,  500.0f);
    const float bfn2     = pb(h[16], 1.0f,   5.0f);
    const float Tbf      = pb(h[17], -5.0f,  2.0f);
    const float Kf       = pb(h[18], 0.0f,   5.0f);
    const float ddf_min  = pb(h[19], 1.5f,   3.0f);
    const float ddf_plus = pb(h[20], 0.0f,   5.0f);
    const float Kcum     = pb(h[21], 0.01f,  0.2f);
    const float Tbm      = pb(h[22], -1.0f,  1.0f);
    const float swi      = pb(h[23], 0.0f,   0.4f);
    const float msw1     = pb(h[26], 50.0f,  500.0f);
    const float msw2     = pb(h[27], 50.0f,  500.0f);

    const float inv_msw1 = 1.0f / msw1;
    const float inv_msw2 = 1.0f / msw2;
    const float inv_x3_1 = 1.0f / x3_1;
    const float inv_x3_2 = 1.0f / x3_2;

    const float* src = stream + (size_t)b * T_STEPS * SLOT_FLOATS;

    float snow = NZ, liq = NZ, cum = NZ, sw1 = NZ, sw2 = NZ;

    auto body = [&](int t) {
        const float4* v = (const float4*)(lds + (t & (DEPTH - 1)) * SLOT_FLOATS);
        const float4 q0 = v[0 * 64 + lane];
        const float4 q1 = v[1 * 64 + lane];
        const float4 q2 = v[2 * 64 + lane];
        const float4 q3 = v[3 * 64 + lane];
        const float4 q4v_ = v[4 * 64 + lane];
        const float4 q5 = v[5 * 64 + lane];

        const float temp = q0.x, pet = q0.y, pshed = q0.z, K = q0.w;
        const float a1 = q1.x, a2 = q1.y, a3s = q1.z, a4 = q1.w;
        const float f0 = q2.x, f1s = q2.y, f2s = q2.z, f3s = q2.w;
        const float f4s = q3.x, f5s = q3.y, c0 = q3.z, c1s = q3.w;
        const float c2s = q4v_.x, c3s = q4v_.y, c4s = q4v_.z, c5s = q4v_.w;
        const float g0p = q5.x, g1c = q5.y;

        const float rain  = (temp >= 0.0f) ? pshed : 0.0f;
        const float snowf = (temp <  0.0f) ? pshed : 0.0f;

        const float refreeze = fminf(liq, Kf * fmaxf(Tbf - temp, 0.0f));
        snow = snow + snowf + refreeze;
        liq  = liq - refreeze;
        const float ddf = ddf_min + ddf_plus * (1.0f - __expf(-Kcum * cum));
        const float melt = fminf(snow, ddf * fmaxf(temp - Tbm, 0.0f));
        snow -= melt;
        cum = (snow < NZ) ? NZ : (cum + melt);
        liq += melt;
        const float overflow = fmaxf(liq - swi * snow, 0.0f);
        liq -= overflow;
        const float wavail = rain + overflow;

        float sat1 = clip01(sw1 * inv_msw1);
        const float dry1 = clip01(1.0f - sat1);
        const float p1 = __powf(sat1, hbv_beta);
        const float p2 = __powf(dry1, vic_bexp);
        const float infil = wavail *
            (K - a1 * p1 + a2 * p2 + a3s * dry1 - a4 * (sat1 * sat1));

        sw1 += infil;
        const float excess = fmaxf(sw1 - msw1, 0.0f);
        sw1 -= excess;
        const float surf = wavail - infil + excess;

        sat1 = clip01(sw1 * inv_msw1);
        const float perc = fminf(g0p * fmaxf(sat1 - sfc, 0.0f), sw1);
        sw1 -= perc; sw2 += perc;

        float sat2 = clip01(sw2 * inv_msw2);
        sat1 = clip01(sw1 * inv_msw1);
        const float capi = fminf(g1c * (1.0f - sat1) * sat2, sw2);
        sw2 -= capi; sw1 += capi;

        sat1 = clip01(sw1 * inv_msw1);
        const float et = fminf(pet * sat1, sw1);
        sw1 -= et;

        sat1 = clip01(sw1 * inv_msw1);
        const float q = sw1 * inv_x3_1;
        const float q4 = (q * q) * (q * q);
        // (1+q4)^(-0.25) via 2x v_rsq + mul (shorter chain than log/mul/exp)
        const float x1 = 1.0f + q4;
        const float pm1 = __frsqrt_rn(__frsqrt_rn(x1) * x1);
        const float gr1 = sw1 * (1.0f - pm1);
        const float pw1 = __powf(sat1, bfn1);
        const float ex1 = __expf(lam * sat1) - 1.0f;
        const float bsum1 = f0 * gr1 + f1s * sw1 + f2s * pw1 +
                            f3s * sat1 + f4s * ex1 +
                            f5s * fmaxf(sat1 - th1, 0.0f);
        const float bf1 = fminf(bsum1, sw1);
        sw1 -= bf1;

        sat2 = clip01(sw2 * inv_msw2);
        const float u = sw2 * inv_x3_2;
        const float u4 = (u * u) * (u * u);
        const float x2 = 1.0f + u4;
        const float pm2 = __frsqrt_rn(__frsqrt_rn(x2) * x2);
        const float gr2 = sw2 * (1.0f - pm2);
        const float pw2 = __powf(sat2, bfn2);
        const float bsum2 = c0 * gr2 + c1s * sw2 + c2s * pw2 +
                            c3s * sat2 + c4s * (sat2 * sat2) +
                            c5s * (sw2 * sat2);
        const float bf2 = fminf(bsum2, sw2);
        sw2 -= bf2;

        const size_t o = (size_t)t * GPAD + g;   // padded: unconditional store
        surf_o[o] = surf;
        base_o[o] = bf1 + bf2;
    };

    // prologue: issue slots 0..6 (42 loads outstanding)
    for (int s = 0; s < DEPTH - 1; ++s)
        load_slot(src + (size_t)s * SLOT_FLOATS, lds + s * SLOT_FLOATS, lane);

    int t = 0;
    for (; t < DEPTH - 1; ++t) {                     // warmup (7 iters)
        load_slot(src + (size_t)(t + DEPTH - 1) * SLOT_FLOATS,
                  lds + ((t + DEPTH - 1) & (DEPTH - 1)) * SLOT_FLOATS, lane);
        asm volatile("s_waitcnt vmcnt(42)" ::: "memory");
        body(t);
    }
    for (; t < T_STEPS - (DEPTH - 1); ++t) {         // steady
        load_slot(src + (size_t)(t + DEPTH - 1) * SLOT_FLOATS,
                  lds + ((t + DEPTH - 1) & (DEPTH - 1)) * SLOT_FLOATS, lane);
        asm volatile("s_waitcnt vmcnt(56)" ::: "memory");
        body(t);
    }
    for (; t < T_STEPS; ++t) {                       // tail (7 iters)
        asm volatile("s_waitcnt vmcnt(0)" ::: "memory");
        body(t);
    }
}

// ---------------------------------------------------------------------------
// Kernel S-B (fallback for small ws): round-1 scan on raw inputs.
// Writes UNPADDED (stride N_GRID) buffers; route gets the stride as an arg.
// ---------------------------------------------------------------------------
__global__ __launch_bounds__(64)
void scan_kernel(const float* __restrict__ xphy,
                 const float* __restrict__ wts,
                 const float* __restrict__ hyb,
                 float* __restrict__ surf_o,
                 float* __restrict__ base_o,
                 unsigned char* __restrict__ gate_o)
{
    const int g = blockIdx.x * 64 + threadIdx.x;
    if (g >= N_GRID) return;

    const float* h = hyb + (size_t)g * 32;
    const float inf_pc   = pb(h[0],  0.0f,   1.0f);
    const float hbv_beta = pb(h[1],  0.5f,   3.0f);
    const float vic_bexp = pb(h[2],  0.001f, 3.0f);
    const float hmets_al = pb(h[3],  0.3f,   1.0f);
    const float x3_1     = pb(h[4],  20.0f,  300.0f);
    const float bfc1     = pb(h[5],  -8.0f,  -2.0f);
    const float bfn1     = pb(h[6],  1.0f,   5.0f);
    const float bfmax1   = pb(h[7],  0.1f,   200.0f);
    const float lam      = pb(h[8],  0.1f,   0.5f);
    const float th1      = pb(h[9],  0.0001f,0.9999f);
    const float max_perc = pb(h[10], 1.0f,   50.0f);
    const float sfc      = pb(h[11], 0.0001f,0.9999f);
    const float crise    = pb(h[12], 0.1f,   50.0f);
    const float bfmax2   = pb(h[13], 0.1f,   100.0f);
    const float x3_2     = pb(h[14], 50.0f,  500.0f);
    const float bfc2     = pb(h[15], -8.0f,  -2.0f);
    const float bfn2     = pb(h[16], 1.0f,   5.0f);
    const float Tbf      = pb(h[17], -5.0f,  2.0f);
    const float Kf       = pb(h[18], 0.0f,   5.0f);
    const float ddf_min  = pb(h[19], 1.5f,   3.0f);
    const float ddf_plus = pb(h[20], 0.0f,   5.0f);
    const float Kcum     = pb(h[21], 0.01f,  0.2f);
    const float Tbm      = pb(h[22], -1.0f,  1.0f);
    const float swi      = pb(h[23], 0.0f,   0.4f);
    const float fc       = pb(h[24], 0.0f,   1.0f);
    const float fs       = pb(h[25], 0.0f,   1.0f);
    const float msw1     = pb(h[26], 50.0f,  500.0f);
    const float msw2     = pb(h[27], 50.0f,  500.0f);

    const float inv_msw1  = 1.0f / msw1;
    const float inv_msw2  = 1.0f / msw2;
    const float canopy_fac = fc * (1.0f - fs);
    const float pow10_1   = powf(10.0f, bfc1);
    const float pow10_2   = powf(10.0f, bfc2);
    const float inv_x3_1  = 1.0f / x3_1;
    const float inv_x3_2  = 1.0f / x3_2;
    const float b1o4      = bfmax1 / expm1f(lam);
    const float b1o5      = bfmax1 / (1.0f - th1);
    const float perc_fac  = max_perc / (1.0f - sfc);

    float snow = NZ, liq = NZ, cum = NZ, sw1 = NZ, sw2 = NZ;

    for (int t = 0; t < T_STEPS; ++t) {
        const size_t idx = (size_t)t * N_GRID + g;
        const float* xp = xphy + idx * 3;
        const float prcp = xp[0], temp = xp[1], pet = xp[2];
        float4 wc0, wc1, wc2, wc3, wc4, wc5;
        const float4* wp = (const float4*)(wts + idx * 24);
        wc0 = wp[0]; wc1 = wp[1]; wc2 = wp[2]; wc3 = wp[3]; wc4 = wp[4]; wc5 = wp[5];

        const float g0 = gatef(wc4.z);
        const float g1 = gatef(wc4.w);
        const float g2 = gatef(wc5.x);
        const float g3 = gatef(wc5.y);
        const float g4 = gatef(wc5.z);
        const float g5 = gatef(wc5.w);

        float rain  = (temp >= 0.0f) ? prcp : 0.0f;
        float snowf = (temp <  0.0f) ? prcp : 0.0f;
        const float canopy = pet * canopy_fac;
        rain  = fmaxf(rain  - canopy * g2, 0.0f);
        snowf = fmaxf(snowf - canopy * g3, 0.0f);

        const float refreeze = fminf(liq, Kf * fmaxf(Tbf - temp, 0.0f));
        snow = snow + snowf + refreeze;
        liq  = liq - refreeze;
        const float ddf = ddf_min + ddf_plus * (1.0f - __expf(-Kcum * cum));
        const float melt = fminf(snow, ddf * fmaxf(temp - Tbm, 0.0f));
        snow -= melt;
        cum = (snow < NZ) ? NZ : (cum + melt);
        liq += melt;
        const float overflow = fmaxf(liq - swi * snow, 0.0f);
        liq -= overflow;
        const float wavail = rain + overflow;

        float sat1 = clip01(sw1 * inv_msw1);
        const float dry1 = clip01(1.0f - sat1);
        const float e0 = __expf(wc0.x), e1 = __expf(wc0.y), e2 = __expf(wc0.z),
                    e3 = __expf(wc0.w), e4 = __expf(wc1.x), e5 = __expf(wc1.y);
        const float rsi = 1.0f / (e0 + e1 + e2 + e3 + e4 + e5);
        const float p1 = __powf(sat1, hbv_beta);
        const float p2 = __powf(dry1, vic_bexp);
        const float infil = wavail * rsi *
            (e0 * inf_pc + e1 * (1.0f - p1) + e2 * p2 +
             e3 * (hmets_al * dry1) + e4 * (1.0f - sat1 * sat1) + e5);

        sw1 += infil;
        const float excess = fmaxf(sw1 - msw1, 0.0f);
        sw1 -= excess;
        const float surf = wavail - infil + excess;

        sat1 = clip01(sw1 * inv_msw1);
        const float perc = fminf(g0 * perc_fac * fmaxf(sat1 - sfc, 0.0f), sw1);
        sw1 -= perc; sw2 += perc;

        float sat2 = clip01(sw2 * inv_msw2);
        sat1 = clip01(sw1 * inv_msw1);
        const float capi = fminf(g1 * crise * (1.0f - sat1) * sat2, sw2);
        sw2 -= capi; sw1 += capi;

        sat1 = clip01(sw1 * inv_msw1);
        const float et = fminf(pet * sat1, sw1);
        sw1 -= et;

        sat1 = clip01(sw1 * inv_msw1);
        const float f0 = __expf(wc1.z), f1 = __expf(wc1.w), f2 = __expf(wc2.x),
                    f3 = __expf(wc2.y), f4 = __expf(wc2.z), f5 = __expf(wc2.w);
        const float rb1 = 1.0f / (f0 + f1 + f2 + f3 + f4 + f5);
        const float q = sw1 * inv_x3_1;
        const float q4 = (q * q) * (q * q);
        const float gr1 = sw1 * (1.0f - __powf(1.0f + q4, -0.25f));
        const float pw1 = __powf(sat1, bfn1);
        const float ex1 = __expf(lam * sat1) - 1.0f;
        const float bsum1 = f0 * gr1 + f1 * (pow10_1 * sw1) + f2 * (bfmax1 * pw1) +
                            f3 * (bfmax1 * sat1) + f4 * (b1o4 * ex1) +
                            f5 * (b1o5 * fmaxf(sat1 - th1, 0.0f));
        const float bf1 = fminf(bsum1 * rb1, sw1);
        sw1 -= bf1;

        sat2 = clip01(sw2 * inv_msw2);
        const float c0 = __expf(wc3.x), c1 = __expf(wc3.y), c2 = __expf(wc3.z),
                    c3 = __expf(wc3.w), c4 = __expf(wc4.x), c5 = __expf(wc4.y);
        const float rb2 = 1.0f / (c0 + c1 + c2 + c3 + c4 + c5);
        const float u = sw2 * inv_x3_2;
        const float u4 = (u * u) * (u * u);
        const float gr2 = sw2 * (1.0f - __powf(1.0f + u4, -0.25f));
        const float pw2 = __powf(sat2, bfn2);
        const float t10 = pow10_2 * sw2;
        const float bsum2 = c0 * gr2 + c1 * t10 + c2 * (bfmax2 * pw2) +
                            c3 * (bfmax2 * sat2) + c4 * (bfmax2 * sat2 * sat2) +
                            c5 * (t10 * sat2);
        const float bf2 = fminf(bsum2 * rb2, sw2);
        sw2 -= bf2;

        surf_o[idx] = surf;
        base_o[idx] = bf1 + bf2;
        gate_o[idx] = (unsigned char)((g4 > 0.5f ? 1 : 0) | (g5 > 0.5f ? 2 : 0));
    }
}

// ---------------------------------------------------------------------------
// Kernel 3: unit-hydrograph routing + gate blend. gp = surf/base row stride.
// ---------------------------------------------------------------------------
__global__ __launch_bounds__(256)
void route_kernel(const float* __restrict__ surf,
                  const float* __restrict__ base,
                  const float* __restrict__ uh1,
                  const float* __restrict__ uh2,
                  const unsigned char* __restrict__ gates,
                  float* __restrict__ out, int gp)
{
    const int g = blockIdx.x * 256 + threadIdx.x;
    if (g >= N_GRID) return;
    const int t = blockIdx.y;
    const size_t o  = (size_t)t * N_GRID + g;
    const size_t op = (size_t)t * gp + g;

    const unsigned char gb = gates[o];
    const float s0 = surf[op];
    const float b0 = base[op];

    float accs = 0.0f, accb = 0.0f;
    #pragma unroll
    for (int lag = 0; lag < UH_LEN; ++lag) {
        const int tt = t - lag;
        const float sv = (tt >= 0) ? surf[(size_t)tt * gp + g] : 0.0f;
        const float bv = (tt >= 0) ? base[(size_t)tt * gp + g] : 0.0f;
        accs += uh1[lag * N_GRID + g] * sv;
        accb += uh2[lag * N_GRID + g] * bv;
    }
    const float qs = (gb & 1) ? accs : s0;
    const float qb = (gb & 2) ? accb : b0;
    out[o] = qs + qb;
}

// ---------------------------------------------------------------------------
extern "C" void kernel_launch(void* const* d_in, const int* in_sizes, int n_in,
                              void* d_out, int out_size, void* d_ws, size_t ws_size,
                              hipStream_t stream)
{
    const float* x_phy = (const float*)d_in[0];   // (T, G, 3)
    const float* wts   = (const float*)d_in[1];   // (T, G, 24)
    const float* hyb   = (const float*)d_in[2];   // (G, 32)
    float* out = (float*)d_out;                   // (T, G)

    const size_t stream_f = (size_t)NB * T_STEPS * SLOT_FLOATS;   // 71,761,920
    const size_t uh_f     = (size_t)UH_LEN * N_GRID;
    const size_t big_need = stream_f * 4 + 2 * TGP * 4 + TG + 2 * uh_f * 4; // ~314 MB

    if (ws_size >= big_need) {
        float* strm = (float*)d_ws;
        float* surf = strm + stream_f;
        float* base = surf + TGP;
        float* uh1  = base + TGP;
        float* uh2  = uh1 + uh_f;
        unsigned char* gbits = (unsigned char*)(uh2 + uh_f);

        prep_kernel<<<dim3((NB * 64) / 256, T_STEPS), dim3(256), 0, stream>>>(
            x_phy, wts, hyb, strm, gbits);
        uh_kernel<<<dim3((N_GRID + 255) / 256), dim3(256), 0, stream>>>(hyb, uh1, uh2);
        scan_stream_kernel<<<dim3(NB), dim3(64), 0, stream>>>(strm, hyb, surf, base);
        route_kernel<<<dim3((N_GRID + 255) / 256, T_STEPS), dim3(256), 0, stream>>>(
            surf, base, uh1, uh2, gbits, out, GPAD);
    } else {
        float* surf = (float*)d_ws;
        float* base = surf + TG;
        float* uh1  = base + TG;
        float* uh2  = uh1 + uh_f;
        unsigned char* gbits = (unsigned char*)(uh2 + uh_f);

        uh_kernel<<<dim3((N_GRID + 255) / 256), dim3(256), 0, stream>>>(hyb, uh1, uh2);
        scan_kernel<<<dim3((N_GRID + 63) / 64), dim3(64), 0, stream>>>(
            x_phy, wts, hyb, surf, base, gbits);
        route_kernel<<<dim3((N_GRID + 255) / 256, T_STEPS), dim3(256), 0, stream>>>(
            surf, base, uh1, uh2, gbits, out, N_GRID);
    }
}